// Round 6
// baseline (321.920 us; speedup 1.0000x reference)
//
#include <hip/hip_runtime.h>
#include <stdint.h>
#include <math.h>

typedef unsigned short u16;
typedef short bf16x8 __attribute__((ext_vector_type(8)));
typedef unsigned short u16x8 __attribute__((ext_vector_type(8)));
typedef unsigned short u16x4 __attribute__((ext_vector_type(4)));
typedef float f32x4 __attribute__((ext_vector_type(4)));

#define LOG2E 1.4426950408889634f

__device__ __forceinline__ float bf2f(u16 u) {
  union { unsigned int i; float f; } v; v.i = ((unsigned int)u) << 16; return v.f;
}
__device__ __forceinline__ u16 f2bf(float f) {
  union { float ff; unsigned int i; } v; v.ff = f;
  unsigned int x = v.i;
  return (u16)((x + 0x7FFFu + ((x >> 16) & 1u)) >> 16);
}

// ---------------------------------------------------------------------------
// fp32 -> bf16 flat convert with scale
// ---------------------------------------------------------------------------
__global__ __launch_bounds__(256)
void cvt_scale(const float* __restrict__ src, u16* __restrict__ dst, long n, float scale)
{
  long i = ((long)blockIdx.x * 256 + threadIdx.x) * 8;
  if (i + 8 > n) return;
  f32x4 a = *(const f32x4*)&src[i];
  f32x4 b = *(const f32x4*)&src[i + 4];
  u16x8 o;
#pragma unroll
  for (int j = 0; j < 4; j++) { o[j] = f2bf(a[j] * scale); o[4 + j] = f2bf(b[j] * scale); }
  *(u16x8*)&dst[i] = o;
}

// ---------------------------------------------------------------------------
// Per-batch transpose+convert: VT[b][n][k] = (bf16)V[b][k][n]. 64x64 tiles.
// ---------------------------------------------------------------------------
__global__ __launch_bounds__(256)
void transcvt_v(const float* __restrict__ V, u16* __restrict__ VT, int S, int E)
{
  __shared__ u16 t[64][72];
  const int b = blockIdx.z;
  const float* Vb = V + (long)b * S * E;
  u16* VTb = VT + (long)b * S * E;
  const int k0 = blockIdx.x * 64, n0 = blockIdx.y * 64;
  const int tid = threadIdx.x;
#pragma unroll
  for (int p = 0; p < 2; p++) {
    int kk = p * 32 + (tid >> 3);
    int nn = (tid & 7) * 8;
    f32x4 a = *(const f32x4*)&Vb[(long)(k0 + kk) * E + n0 + nn];
    f32x4 c = *(const f32x4*)&Vb[(long)(k0 + kk) * E + n0 + nn + 4];
#pragma unroll
    for (int j = 0; j < 4; j++) { t[nn + j][kk] = f2bf(a[j]); t[nn + 4 + j][kk] = f2bf(c[j]); }
  }
  __syncthreads();
#pragma unroll
  for (int p = 0; p < 2; p++) {
    int nn = p * 32 + (tid >> 3);
    int kk = (tid & 7) * 8;
    u16x8 u;
#pragma unroll
    for (int j = 0; j < 8; j++) u[j] = t[nn][kk + j];
    *(u16x8*)&VTb[(long)(n0 + nn) * S + k0 + kk] = u;
  }
}

// ---------------------------------------------------------------------------
// FAST GEMM (BT layout): C[g][n] = sum_k (aScale*A[g][k]) * B[n][k]
//  256x128 tile, 512 threads / 8 waves in a 4x2 wave grid (each wave 64x64,
//  4x4 16x16x32 MFMA acc). Fragment-packed LDS (conflict-free b128),
//  BK=64, 2-barrier K-loop (the empirically best structure: R2/R5).
//  AF32/BF32: fp32 sources converted (and A scaled) during staging.
//  XCD swizzle: y-bands per XCD for L2 residency of the shared B operand.
// ---------------------------------------------------------------------------
template<int AF32, int BF32, int COUT>
__global__ __launch_bounds__(512, 4)
void gemm_fast(const void* __restrict__ A_, int lda, long aRowOff,
               const void* __restrict__ B_, int ldb, long bBatchStride,
               void* __restrict__ Cp, int ldc, long cRowOff,
               int K, float aScale, long g0, int S)
{
  // XCD-aware swizzle: assign each XCD (assumed id = linear%8) a y-band.
  int gx = gridDim.x, gy = gridDim.y;
  int bx = blockIdx.x, by = blockIdx.y;
  if ((gy & 7) == 0) {
    int f = by * gx + bx;
    int band = gy >> 3;
    int u = f & 7, v = f >> 3;
    by = u * band + (v % band);
    bx = v / band;
  }
  const int tid  = threadIdx.x;
  const int lane = tid & 63;
  const int wave = tid >> 6;
  const long gTile = g0 + (long)by * 256;
  const int  b     = (int)(gTile / S);
  const int  nTile = bx * 128;

  // fragment-packed: subtile (ss, ks) holds rows 16*ss..+15, k=ks*32+(l>>4)*8,
  // lane l's 16B at u16 index ss*1024 + ks*512 + l*8.
  __shared__ u16 As[16384];   // 16 ss (256 rows) x 2 ks -> 32 KB
  __shared__ u16 Bs[8192];    //  8 ss (128 rows) x 2 ks -> 16 KB

  const float* Af = (const float*)A_ + (gTile - aRowOff) * (long)lda;
  const u16*   Ab = (const u16*)A_   + (gTile - aRowOff) * (long)lda;
  const float* Bf = (const float*)B_ + (long)b * bBatchStride;
  const u16*   Bb = (const u16*)B_   + (long)b * bBatchStride;

  const int l15 = lane & 15;
  const int lc  = (lane >> 4) * 8;

  // staging: wave w stages A subtiles ss=2w,2w+1 (rows 32w..32w+31) and
  // B subtile ss=w (rows nTile+16w..+15), both ks halves.
  const long ar0 = (long)(wave * 32 + l15) * lda + lc;
  const long ar1 = ar0 + (long)16 * lda;
  const long br0 = (long)(nTile + wave * 16 + l15) * ldb + lc;
  u16* as0 = As + wave * 2048 + lane * 8;
  u16* bs0 = Bs + wave * 1024 + lane * 8;

  f32x4 acc[4][4];
#pragma unroll
  for (int i = 0; i < 4; i++)
#pragma unroll
    for (int j = 0; j < 4; j++) acc[i][j] = (f32x4){0.f, 0.f, 0.f, 0.f};

  const int wm4 = (wave >> 1) * 4;   // A subtile base (wave row = wave>>1, 0..3)
  const int wn4 = (wave & 1) * 4;    // B subtile base (wave col = wave&1, 0..1)

  for (int k0 = 0; k0 < K; k0 += 64) {
    // ---- stage A ----
    if (AF32) {
      f32x4 x0 = *(const f32x4*)&Af[ar0 + k0],      x1 = *(const f32x4*)&Af[ar0 + k0 + 4];
      f32x4 x2 = *(const f32x4*)&Af[ar0 + k0 + 32], x3 = *(const f32x4*)&Af[ar0 + k0 + 36];
      f32x4 x4 = *(const f32x4*)&Af[ar1 + k0],      x5 = *(const f32x4*)&Af[ar1 + k0 + 4];
      f32x4 x6 = *(const f32x4*)&Af[ar1 + k0 + 32], x7 = *(const f32x4*)&Af[ar1 + k0 + 36];
      u16x8 w0, w1, w2, w3;
#pragma unroll
      for (int j = 0; j < 4; j++) {
        w0[j] = f2bf(x0[j] * aScale); w0[4 + j] = f2bf(x1[j] * aScale);
        w1[j] = f2bf(x2[j] * aScale); w1[4 + j] = f2bf(x3[j] * aScale);
        w2[j] = f2bf(x4[j] * aScale); w2[4 + j] = f2bf(x5[j] * aScale);
        w3[j] = f2bf(x6[j] * aScale); w3[4 + j] = f2bf(x7[j] * aScale);
      }
      *(u16x8*)&as0[0]    = w0;   // ss=2w, ks=0
      *(u16x8*)&as0[512]  = w1;   // ss=2w, ks=1
      *(u16x8*)&as0[1024] = w2;   // ss=2w+1, ks=0
      *(u16x8*)&as0[1536] = w3;   // ss=2w+1, ks=1
    } else {
      u16x8 a0 = *(const u16x8*)&Ab[ar0 + k0];
      u16x8 a1 = *(const u16x8*)&Ab[ar0 + k0 + 32];
      u16x8 a2 = *(const u16x8*)&Ab[ar1 + k0];
      u16x8 a3 = *(const u16x8*)&Ab[ar1 + k0 + 32];
      *(u16x8*)&as0[0]    = a0;
      *(u16x8*)&as0[512]  = a1;
      *(u16x8*)&as0[1024] = a2;
      *(u16x8*)&as0[1536] = a3;
    }
    // ---- stage B ----
    if (BF32) {
      f32x4 y0 = *(const f32x4*)&Bf[br0 + k0],      y1 = *(const f32x4*)&Bf[br0 + k0 + 4];
      f32x4 y2 = *(const f32x4*)&Bf[br0 + k0 + 32], y3 = *(const f32x4*)&Bf[br0 + k0 + 36];
      u16x8 w0, w1;
#pragma unroll
      for (int j = 0; j < 4; j++) {
        w0[j] = f2bf(y0[j]); w0[4 + j] = f2bf(y1[j]);
        w1[j] = f2bf(y2[j]); w1[4 + j] = f2bf(y3[j]);
      }
      *(u16x8*)&bs0[0]   = w0;
      *(u16x8*)&bs0[512] = w1;
    } else {
      u16x8 b0 = *(const u16x8*)&Bb[br0 + k0];
      u16x8 b1 = *(const u16x8*)&Bb[br0 + k0 + 32];
      *(u16x8*)&bs0[0]   = b0;
      *(u16x8*)&bs0[512] = b1;
    }
    __syncthreads();

#pragma unroll
    for (int ks = 0; ks < 2; ks++) {
      bf16x8 af[4], bfr[4];
#pragma unroll
      for (int rt = 0; rt < 4; rt++)
        af[rt] = *(const bf16x8*)&As[(wm4 + rt) * 1024 + ks * 512 + lane * 8];
#pragma unroll
      for (int ct = 0; ct < 4; ct++)
        bfr[ct] = *(const bf16x8*)&Bs[(wn4 + ct) * 1024 + ks * 512 + lane * 8];
#pragma unroll
      for (int rt = 0; rt < 4; rt++)
#pragma unroll
        for (int ct = 0; ct < 4; ct++)
          acc[rt][ct] = __builtin_amdgcn_mfma_f32_16x16x32_bf16(af[rt], bfr[ct], acc[rt][ct], 0, 0, 0);
    }
    __syncthreads();
  }

  // epilogue: C/D layout col = lane&15, row = (lane>>4)*4 + reg (verified)
  const int qm = (wave >> 1) * 64;
  const int qn = (wave & 1) * 64;
  const int lr = (lane >> 4) * 4;
#pragma unroll
  for (int rt = 0; rt < 4; rt++) {
#pragma unroll
    for (int ct = 0; ct < 4; ct++) {
      long gr = gTile + qm + rt * 16 + lr;
      int  cc = nTile + qn + ct * 16 + l15;
#pragma unroll
      for (int i = 0; i < 4; i++) {
        if (COUT == 0)
          ((u16*)Cp)[(gr + i - cRowOff) * (long)ldc + cc] = f2bf(acc[rt][ct][i]);
        else
          ((float*)Cp)[(gr + i - cRowOff) * (long)ldc + cc] = acc[rt][ct][i];
      }
    }
  }
}

// ---------------------------------------------------------------------------
// SLOW fallback GEMM (fp32 sources, 128-tiles) — only if ws is tiny.
// ---------------------------------------------------------------------------
template<int BMODE, int HASMASK, int COUT>
__global__ __launch_bounds__(256, 2)
void gemm_slow(const void* __restrict__ Ap, int lda, long aRowOff,
               const void* __restrict__ Bp, int ldb, long bBatchStride,
               void* __restrict__ Cp, int ldc, long cRowOff,
               const float* __restrict__ maskf,
               int K, float scale, long g0, int S)
{
  const int tid  = threadIdx.x;
  const int lane = tid & 63;
  const int wave = tid >> 6;
  const long gTile = g0 + (long)blockIdx.y * 128;
  const int  b     = (int)(gTile / S);
  const int  nTile = blockIdx.x * 128;

  __shared__ u16 As[128][40];
  __shared__ u16 Bs[128][40];

  const int qm = (wave >> 1) * 64;
  const int qn = (wave & 1) * 64;

  f32x4 acc[4][4];
#pragma unroll
  for (int i = 0; i < 4; i++)
#pragma unroll
    for (int j = 0; j < 4; j++) acc[i][j] = (f32x4){0.f, 0.f, 0.f, 0.f};

  const float* Af = (const float*)Ap + (gTile - aRowOff) * (long)lda;
  const u16*   Ab16 = (const u16*)Ap + (gTile - aRowOff) * (long)lda;
  const float* Bf = (const float*)Bp + (long)b * bBatchStride;

  const int lm = lane & 15;
  const int lk = (lane >> 4) * 8;

  for (int k0 = 0; k0 < K; k0 += 32) {
    if (BMODE == 1) {
      int srow = tid >> 2, scol = (tid & 3) * 8;
#pragma unroll
      for (int p = 0; p < 2; p++) {
        int r = p * 64 + srow;
        *(u16x8*)&As[r][scol] = *(const u16x8*)&Ab16[(long)r * lda + k0 + scol];
      }
    } else {
      int srow = tid >> 3, scol = (tid & 7) * 4;
#pragma unroll
      for (int p = 0; p < 4; p++) {
        int r = p * 32 + srow;
        f32x4 a = *(const f32x4*)&Af[(long)r * lda + k0 + scol];
        u16x4 o;
#pragma unroll
        for (int j = 0; j < 4; j++) o[j] = f2bf(a[j]);
        *(u16x4*)&As[r][scol] = o;
      }
    }
    if (BMODE == 0) {
      int srow = tid >> 3, scol = (tid & 7) * 4;
#pragma unroll
      for (int p = 0; p < 4; p++) {
        int r = p * 32 + srow;
        f32x4 a = *(const f32x4*)&Bf[(long)(nTile + r) * ldb + k0 + scol];
        u16x4 o;
#pragma unroll
        for (int j = 0; j < 4; j++) o[j] = f2bf(a[j]);
        *(u16x4*)&Bs[r][scol] = o;
      }
    }
    __syncthreads();

    bf16x8 af[4], bfr[4];
#pragma unroll
    for (int rt = 0; rt < 4; rt++)
      af[rt] = *(const bf16x8*)&As[qm + rt * 16 + lm][lk];
    if (BMODE == 0) {
#pragma unroll
      for (int ct = 0; ct < 4; ct++)
        bfr[ct] = *(const bf16x8*)&Bs[qn + ct * 16 + lm][lk];
    } else {
#pragma unroll
      for (int ct = 0; ct < 4; ct++) {
        const float* vp = Bf + (long)(k0 + lk) * ldb + nTile + qn + ct * 16 + lm;
#pragma unroll
        for (int j = 0; j < 8; j++) bfr[ct][j] = (short)f2bf(vp[(long)j * ldb]);
      }
    }
#pragma unroll
    for (int rt = 0; rt < 4; rt++)
#pragma unroll
      for (int ct = 0; ct < 4; ct++)
        acc[rt][ct] = __builtin_amdgcn_mfma_f32_16x16x32_bf16(af[rt], bfr[ct], acc[rt][ct], 0, 0, 0);
    __syncthreads();
  }

  const int lr = (lane >> 4) * 4;
#pragma unroll
  for (int rt = 0; rt < 4; rt++) {
#pragma unroll
    for (int ct = 0; ct < 4; ct++) {
      long gr = gTile + qm + rt * 16 + lr;
      int  cc = nTile + qn + ct * 16 + lm;
#pragma unroll
      for (int i = 0; i < 4; i++) {
        float v = acc[rt][ct][i] * scale;
        if (HASMASK) v += maskf[(gr + i) * (long)ldc + cc];
        if (COUT == 0)
          ((u16*)Cp)[(gr + i - cRowOff) * (long)ldc + cc] = f2bf(v);
        else
          ((float*)Cp)[(gr + i - cRowOff) * (long)ldc + cc] = v;
      }
    }
  }
}

// ---------------------------------------------------------------------------
// Row softmax in place, optionally adding fp32 mask first. ncols == 2048.
// ---------------------------------------------------------------------------
template<int HASMASK>
__global__ __launch_bounds__(256)
void softmax_rows(u16* __restrict__ Sbuf, const float* __restrict__ mask,
                  long g0, int ncols)
{
  const long row = blockIdx.x;
  u16* rp = Sbuf + row * (long)ncols;
  const int tid = threadIdx.x;

  u16x8 u = *(const u16x8*)&rp[tid * 8];
  float x[8];
  if (HASMASK) {
    const float* mp = mask + (g0 + row) * (long)ncols + tid * 8;
    f32x4 m0 = *(const f32x4*)&mp[0];
    f32x4 m1 = *(const f32x4*)&mp[4];
#pragma unroll
    for (int i = 0; i < 4; i++) { x[i] = bf2f(u[i]) + m0[i]; x[4 + i] = bf2f(u[4 + i]) + m1[i]; }
  } else {
#pragma unroll
    for (int i = 0; i < 8; i++) x[i] = bf2f(u[i]);
  }
  float m = -3.0e38f;
#pragma unroll
  for (int i = 0; i < 8; i++) m = fmaxf(m, x[i]);
#pragma unroll
  for (int off = 32; off; off >>= 1) m = fmaxf(m, __shfl_xor(m, off, 64));
  __shared__ float redm[4];
  if ((tid & 63) == 0) redm[tid >> 6] = m;
  __syncthreads();
  m = fmaxf(fmaxf(redm[0], redm[1]), fmaxf(redm[2], redm[3]));

  float e[8];
  float s = 0.f;
#pragma unroll
  for (int i = 0; i < 8; i++) { e[i] = exp2f((x[i] - m) * LOG2E); s += e[i]; }
#pragma unroll
  for (int off = 32; off; off >>= 1) s += __shfl_xor(s, off, 64);
  __shared__ float reds[4];
  if ((tid & 63) == 0) reds[tid >> 6] = s;
  __syncthreads();
  s = reds[0] + reds[1] + reds[2] + reds[3];

  float inv = 1.0f / s;
  u16x8 o;
#pragma unroll
  for (int i = 0; i < 8; i++) o[i] = f2bf(e[i] * inv);
  *(u16x8*)&rp[tid * 8] = o;
}

extern "C" void kernel_launch(void* const* d_in, const int* in_sizes, int n_in,
                              void* d_out, int out_size, void* d_ws, size_t ws_size,
                              hipStream_t stream)
{
  const float* Q    = (const float*)d_in[0];
  const float* Km   = (const float*)d_in[1];
  const float* V    = (const float*)d_in[2];
  const float* mask = (const float*)d_in[3];
  float* out = (float*)d_out;

  const long qsz = in_sizes[0];          // B*S*E
  const long msz = in_sizes[3];          // B*S*S
  const long E = 1024;
  const long S = (msz / qsz) * E;        // 2048
  const long B = qsz / (S * E);          // 4
  const long G = B * S;
  const float scale = 1.0f / sqrtf((float)E);

  const size_t vtB    = (size_t)qsz * 2;        // V^T bf16 (16.8 MB)
  const size_t sbFull = (size_t)G * S * 2;      // full score buffer (33.5 MB)
  const size_t strip1 = (size_t)256 * S * 2;    // minimal 256-row strip

  char* w = (char*)d_ws;
  size_t avail = ws_size;
  u16 *VTb = nullptr, *Qb = nullptr, *Kb = nullptr;
  const bool haveVT = (avail >= vtB + strip1);
  if (haveVT) { VTb = (u16*)w; w += vtB; avail -= vtB; }
  // pre-convert Q/K only when it doesn't cost us single-pass capacity
  const bool haveQK = haveVT && (avail >= 2 * vtB + sbFull);
  if (haveQK) { Qb = (u16*)w; w += vtB; Kb = (u16*)w; w += vtB; avail -= 2 * vtB; }

  if (haveVT) {
    long Rmax = (long)((avail / ((size_t)S * 2)) / 256) * 256;
    if (Rmax > G) Rmax = G;
    u16* Sbuf = (u16*)w;
    if (Rmax >= 256) {
      if (haveQK) {
        cvt_scale<<<dim3((unsigned)(qsz / 2048)), 256, 0, stream>>>(Q, Qb, qsz, scale);
        cvt_scale<<<dim3((unsigned)(qsz / 2048)), 256, 0, stream>>>(Km, Kb, qsz, 1.0f);
      }
      transcvt_v<<<dim3(S / 64, E / 64, B), 256, 0, stream>>>(V, VTb, (int)S, (int)E);

      for (long g0 = 0; g0 < G; g0 += Rmax) {
        const long R = (G - g0 < Rmax) ? (G - g0) : Rmax;
        // 1) raw scaled scores (mask deferred to softmax)
        if (haveQK)
          gemm_fast<0, 0, 0><<<dim3(S / 128, R / 256), 512, 0, stream>>>(
              Qb, (int)E, 0L, Kb, (int)E, S * E,
              Sbuf, (int)S, g0, (int)E, 1.0f, g0, (int)S);
        else
          gemm_fast<1, 1, 0><<<dim3(S / 128, R / 256), 512, 0, stream>>>(
              Q, (int)E, 0L, Km, (int)E, S * E,
              Sbuf, (int)S, g0, (int)E, scale, g0, (int)S);
        // 2) softmax(scores + mask)
        softmax_rows<1><<<dim3(R), 256, 0, stream>>>(Sbuf, mask, g0, (int)S);
        // 3) out = P V
        gemm_fast<0, 0, 1><<<dim3(E / 128, R / 256), 512, 0, stream>>>(
            Sbuf, (int)S, g0, VTb, (int)S, E * S,
            out, (int)E, 0L, (int)S, 1.0f, g0, (int)S);
      }
      return;
    }
  }

  // ---- tiny-ws fallback: 128-tile slow kernels, strip loop ----
  u16* Sbuf = (u16*)d_ws;
  long Rmax = (long)((ws_size / ((size_t)S * 2)) / 128) * 128;
  if (Rmax > G) Rmax = G;
  if (Rmax < 128) Rmax = 128;
  for (long g0 = 0; g0 < G; g0 += Rmax) {
    const long R = (G - g0 < Rmax) ? (G - g0) : Rmax;
    gemm_slow<0, 1, 0><<<dim3(S / 128, R / 128), 256, 0, stream>>>(
        Q, (int)E, 0L, Km, (int)E, S * E,
        Sbuf, (int)S, g0, mask, (int)E, scale, g0, (int)S);
    softmax_rows<0><<<dim3(R), 256, 0, stream>>>(Sbuf, nullptr, g0, (int)S);
    gemm_slow<1, 0, 1><<<dim3(E / 128, R / 128), 256, 0, stream>>>(
        Sbuf, (int)S, g0, V, (int)E, S * E,
        out, (int)E, 0L, nullptr, (int)S, 1.0f, g0, (int)S);
  }
}